// Round 1
// baseline (420.565 us; speedup 1.0000x reference)
//
#include <hip/hip_runtime.h>

// MoE top-2 FFN, split-bf16 MFMA implementation.
// Pipeline: init -> gate(top2) -> scan -> scatter -> out=gate*b2 ->
//           transpose W1/W2 to [e][n][k] bf16 hi/lo -> GEMM1 (h=relu(xW1+b1))
//           -> GEMM2 (out += gate * h W2) with f32 atomics.

#define T_TOKENS 4096
#define D_MOD 512
#define N_EXP 8
#define D_FF 2048
#define TM 64            // row tile (pairs)
#define P_CAP 8704       // 136 * 64 >= 8192 + 8*63 worst-case padded pairs

typedef __attribute__((ext_vector_type(4))) float f32x4_t;
typedef __attribute__((ext_vector_type(8))) short sh8;
typedef __attribute__((ext_vector_type(4))) short sh4;

__device__ __forceinline__ unsigned short f2bh(float f) {
  unsigned u = __float_as_uint(f);
  unsigned r = (u + 0x7FFFu + ((u >> 16) & 1u)) >> 16;   // RNE
  return (unsigned short)r;
}
__device__ __forceinline__ float bh2f(unsigned short h) {
  return __uint_as_float(((unsigned)h) << 16);
}
// rows are 128B (64 bf16); XOR-swizzle bits 4..6 by row&7 (guide G4 pattern)
__device__ __forceinline__ int swz(int row, int b) {
  return row * 128 + (b ^ ((row & 7) << 4));
}

// ---------------- routing kernels ----------------

__global__ void k_init(int* counts, int* pair_token, float* pair_gate) {
  int idx = blockIdx.x * 256 + threadIdx.x;
  if (idx < P_CAP) { pair_token[idx] = -1; pair_gate[idx] = 0.f; }
  if (idx < N_EXP) counts[idx] = 0;
}

__global__ __launch_bounds__(256) void k_gate(const float* __restrict__ x,
    const float* __restrict__ Wg, const float* __restrict__ bg,
    int* __restrict__ top_i, float* __restrict__ gates, int* __restrict__ counts) {
  int t = blockIdx.x * 256 + threadIdx.x;
  float acc[8];
#pragma unroll
  for (int e = 0; e < 8; ++e) acc[e] = bg[e];
  const float* xr = x + (size_t)t * D_MOD;
  for (int d = 0; d < D_MOD; d += 4) {
    float4 xv = *(const float4*)(xr + d);
    float xs[4] = {xv.x, xv.y, xv.z, xv.w};
#pragma unroll
    for (int j = 0; j < 4; ++j) {
      const float* wr = Wg + (size_t)(d + j) * 8;
      float4 w0 = *(const float4*)wr;
      float4 w1 = *(const float4*)(wr + 4);
      acc[0] += xs[j] * w0.x; acc[1] += xs[j] * w0.y;
      acc[2] += xs[j] * w0.z; acc[3] += xs[j] * w0.w;
      acc[4] += xs[j] * w1.x; acc[5] += xs[j] * w1.y;
      acc[6] += xs[j] * w1.z; acc[7] += xs[j] * w1.w;
    }
  }
  int e0 = 0; float m0 = acc[0];
#pragma unroll
  for (int e = 1; e < 8; ++e) if (acc[e] > m0) { m0 = acc[e]; e0 = e; }
  int e1 = -1; float m1 = -3.4e38f;
#pragma unroll
  for (int e = 0; e < 8; ++e) if (e != e0 && acc[e] > m1) { m1 = acc[e]; e1 = e; }
  // renormalized top-2 softmax == sigmoid of logit gap
  float g0 = 1.f / (1.f + expf(m1 - m0));
  float g1 = 1.f - g0;
  top_i[t * 2] = e0; top_i[t * 2 + 1] = e1;
  gates[t * 2] = g0; gates[t * 2 + 1] = g1;
  atomicAdd(&counts[e0], 1);
  atomicAdd(&counts[e1], 1);
}

__global__ void k_scan(const int* counts, int* offsets, int* cursor) {
  if (threadIdx.x == 0 && blockIdx.x == 0) {
    int o = 0;
    for (int e = 0; e < N_EXP; ++e) {
      offsets[e] = o; cursor[e] = o;
      o += (counts[e] + TM - 1) & ~(TM - 1);
    }
    offsets[N_EXP] = o;
  }
}

__global__ void k_scatter(const int* top_i, const float* gates, int* cursor,
                          int* pair_token, float* pair_gate) {
  int t = blockIdx.x * 256 + threadIdx.x;
#pragma unroll
  for (int k = 0; k < 2; ++k) {
    int e = top_i[t * 2 + k];
    int pos = atomicAdd(&cursor[e], 1);
    pair_token[pos] = t;
    pair_gate[pos] = gates[t * 2 + k];
  }
}

__global__ void k_outinit(const int* __restrict__ top_i, const float* __restrict__ gates,
                          const float* __restrict__ b2, float* __restrict__ out) {
  int idx = blockIdx.x * 256 + threadIdx.x;    // T*512
  int t = idx >> 9, d = idx & 511;
  float v = gates[t * 2] * b2[top_i[t * 2] * D_MOD + d] +
            gates[t * 2 + 1] * b2[top_i[t * 2 + 1] * D_MOD + d];
  out[idx] = v;
}

// -------------- weight transpose + hi/lo split: W[e][R][C] -> Wt[e][C][R] --------------

__global__ __launch_bounds__(256) void k_transpose(const float* __restrict__ W,
    unsigned short* __restrict__ Wh, unsigned short* __restrict__ Wl, int R, int C) {
  __shared__ float tile[32][33];
  int e = blockIdx.z;
  int c0 = blockIdx.x * 32, r0 = blockIdx.y * 32;
  const float* src = W + (size_t)e * R * C;
  int tx = threadIdx.x & 31, ty = threadIdx.x >> 5;
#pragma unroll
  for (int i = 0; i < 4; ++i) {
    int r = ty + i * 8;
    tile[r][tx] = src[(size_t)(r0 + r) * C + c0 + tx];
  }
  __syncthreads();
#pragma unroll
  for (int i = 0; i < 4; ++i) {
    int cc = ty + i * 8;
    float v = tile[tx][cc];
    unsigned short h = f2bh(v);
    unsigned short l = f2bh(v - bh2f(h));
    size_t oidx = ((size_t)e * C + c0 + cc) * R + r0 + tx;
    Wh[oidx] = h; Wl[oidx] = l;
  }
}

// -------------- GEMM1: h[row][f] = relu( X[tok(row)] @ W1 + b1 ) --------------
// 64x128 tile, K=512 in 64-steps. 4 waves (2x2), wave tile 32x64, 16x16x32 MFMA.

__global__ __launch_bounds__(256) void k_ffn1(const float* __restrict__ x,
    const unsigned short* __restrict__ W1h, const unsigned short* __restrict__ W1l,
    const float* __restrict__ b1, const int* __restrict__ pair_token,
    const int* __restrict__ offsets, float* __restrict__ hbuf, int row_base) {
  int total = offsets[N_EXP];
  int row0 = row_base + blockIdx.x * TM;
  if (row0 >= total) return;
  int f0 = blockIdx.y * 128;
  int e = 0;
  while (offsets[e + 1] <= row0) ++e;

  __shared__ int tok[TM];
  __shared__ short Ah[TM * 64], Al[TM * 64];     // 8KB each
  __shared__ short Bh[128 * 64], Bl[128 * 64];   // 16KB each
  int tid = threadIdx.x;
  if (tid < TM) tok[tid] = pair_token[row0 + tid];
  __syncthreads();

  int lane = tid & 63, wid = tid >> 6;
  int wr = wid & 1, wc = wid >> 1;
  int lrow = lane & 15, kblk = lane >> 4;
  const f32x4_t zero = {0.f, 0.f, 0.f, 0.f};
  f32x4_t acc[2][4];
#pragma unroll
  for (int a = 0; a < 2; ++a)
#pragma unroll
    for (int b = 0; b < 4; ++b) acc[a][b] = zero;

  const size_t wbase = (size_t)e * D_FF * D_MOD;
  for (int ks = 0; ks < D_MOD / 64; ++ks) {
    int k0 = ks * 64;
    // stage A (gathered token rows), fp32 -> bf16 hi/lo
#pragma unroll
    for (int i = 0; i < 4; ++i) {
      int idx = tid + i * 256;           // 1024 float4 = 64 rows x 16
      int r = idx >> 4, c4 = idx & 15;
      int t_ = tok[r];
      float4 v = make_float4(0.f, 0.f, 0.f, 0.f);
      if (t_ >= 0) v = *(const float4*)(x + (size_t)t_ * D_MOD + k0 + c4 * 4);
      unsigned short h0 = f2bh(v.x), h1 = f2bh(v.y), h2 = f2bh(v.z), h3 = f2bh(v.w);
      sh4 hv = {(short)h0, (short)h1, (short)h2, (short)h3};
      sh4 lv = {(short)f2bh(v.x - bh2f(h0)), (short)f2bh(v.y - bh2f(h1)),
                (short)f2bh(v.z - bh2f(h2)), (short)f2bh(v.w - bh2f(h3))};
      int off = swz(r, c4 * 8);
      *(sh4*)((char*)Ah + off) = hv;
      *(sh4*)((char*)Al + off) = lv;
    }
    // stage B from pre-transposed bf16 (k-contiguous)
#pragma unroll
    for (int i = 0; i < 4; ++i) {
      int idx = tid + i * 256;           // 1024 sh8 = 128 cols x 8
      int col = idx >> 3, kb = idx & 7;
      size_t g = wbase + (size_t)(f0 + col) * D_MOD + k0 + kb * 8;
      sh8 vh = *(const sh8*)(W1h + g);
      sh8 vl = *(const sh8*)(W1l + g);
      int off = swz(col, kb * 16);
      *(sh8*)((char*)Bh + off) = vh;
      *(sh8*)((char*)Bl + off) = vl;
    }
    __syncthreads();
#pragma unroll
    for (int kk = 0; kk < 2; ++kk) {
      sh8 ah[2], al[2], bh[4], bl[4];
#pragma unroll
      for (int rt = 0; rt < 2; ++rt) {
        int row = wr * 32 + rt * 16 + lrow;
        int off = swz(row, kk * 64 + kblk * 16);
        ah[rt] = *(const sh8*)((char*)Ah + off);
        al[rt] = *(const sh8*)((char*)Al + off);
      }
#pragma unroll
      for (int ct = 0; ct < 4; ++ct) {
        int col = wc * 64 + ct * 16 + lrow;
        int off = swz(col, kk * 64 + kblk * 16);
        bh[ct] = *(const sh8*)((char*)Bh + off);
        bl[ct] = *(const sh8*)((char*)Bl + off);
      }
#pragma unroll
      for (int rt = 0; rt < 2; ++rt)
#pragma unroll
        for (int ct = 0; ct < 4; ++ct) {
          acc[rt][ct] = __builtin_amdgcn_mfma_f32_16x16x32_bf16(ah[rt], bh[ct], acc[rt][ct], 0, 0, 0);
          acc[rt][ct] = __builtin_amdgcn_mfma_f32_16x16x32_bf16(ah[rt], bl[ct], acc[rt][ct], 0, 0, 0);
          acc[rt][ct] = __builtin_amdgcn_mfma_f32_16x16x32_bf16(al[rt], bh[ct], acc[rt][ct], 0, 0, 0);
        }
    }
    __syncthreads();
  }
  int crow = row0 - row_base;
#pragma unroll
  for (int rt = 0; rt < 2; ++rt)
#pragma unroll
    for (int ct = 0; ct < 4; ++ct)
#pragma unroll
      for (int r = 0; r < 4; ++r) {
        int row = wr * 32 + rt * 16 + kblk * 4 + r;   // C/D: row=(l>>4)*4+reg
        int f = wc * 64 + ct * 16 + lrow;             // col = l&15
        float v = acc[rt][ct][r] + b1[e * D_FF + f0 + f];
        hbuf[(size_t)(crow + row) * D_FF + f0 + f] = fmaxf(v, 0.f);
      }
}

// -------------- GEMM2: out[tok(row)] += gate(row) * ( h @ W2 ) --------------

__global__ __launch_bounds__(256) void k_ffn2(const float* __restrict__ hbuf,
    const unsigned short* __restrict__ W2h, const unsigned short* __restrict__ W2l,
    const int* __restrict__ pair_token, const float* __restrict__ pair_gate,
    const int* __restrict__ offsets, float* __restrict__ out, int row_base) {
  int total = offsets[N_EXP];
  int row0 = row_base + blockIdx.x * TM;
  if (row0 >= total) return;
  int n0 = blockIdx.y * 128;
  int e = 0;
  while (offsets[e + 1] <= row0) ++e;

  __shared__ int tok[TM];
  __shared__ float gt[TM];
  __shared__ short Ah[TM * 64], Al[TM * 64];
  __shared__ short Bh[128 * 64], Bl[128 * 64];
  int tid = threadIdx.x;
  if (tid < TM) { tok[tid] = pair_token[row0 + tid]; gt[tid] = pair_gate[row0 + tid]; }
  __syncthreads();

  int lane = tid & 63, wid = tid >> 6;
  int wr = wid & 1, wc = wid >> 1;
  int lrow = lane & 15, kblk = lane >> 4;
  const f32x4_t zero = {0.f, 0.f, 0.f, 0.f};
  f32x4_t acc[2][4];
#pragma unroll
  for (int a = 0; a < 2; ++a)
#pragma unroll
    for (int b = 0; b < 4; ++b) acc[a][b] = zero;

  int crow = row0 - row_base;
  const size_t wbase = (size_t)e * D_MOD * D_FF;
  for (int ks = 0; ks < D_FF / 64; ++ks) {
    int k0 = ks * 64;
#pragma unroll
    for (int i = 0; i < 4; ++i) {
      int idx = tid + i * 256;
      int r = idx >> 4, c4 = idx & 15;
      float4 v = *(const float4*)(hbuf + (size_t)(crow + r) * D_FF + k0 + c4 * 4);
      unsigned short h0 = f2bh(v.x), h1 = f2bh(v.y), h2 = f2bh(v.z), h3 = f2bh(v.w);
      sh4 hv = {(short)h0, (short)h1, (short)h2, (short)h3};
      sh4 lv = {(short)f2bh(v.x - bh2f(h0)), (short)f2bh(v.y - bh2f(h1)),
                (short)f2bh(v.z - bh2f(h2)), (short)f2bh(v.w - bh2f(h3))};
      int off = swz(r, c4 * 8);
      *(sh4*)((char*)Ah + off) = hv;
      *(sh4*)((char*)Al + off) = lv;
    }
#pragma unroll
    for (int i = 0; i < 4; ++i) {
      int idx = tid + i * 256;
      int col = idx >> 3, kb = idx & 7;
      size_t g = wbase + (size_t)(n0 + col) * D_FF + k0 + kb * 8;
      sh8 vh = *(const sh8*)(W2h + g);
      sh8 vl = *(const sh8*)(W2l + g);
      int off = swz(col, kb * 16);
      *(sh8*)((char*)Bh + off) = vh;
      *(sh8*)((char*)Bl + off) = vl;
    }
    __syncthreads();
#pragma unroll
    for (int kk = 0; kk < 2; ++kk) {
      sh8 ah[2], al[2], bh[4], bl[4];
#pragma unroll
      for (int rt = 0; rt < 2; ++rt) {
        int row = wr * 32 + rt * 16 + lrow;
        int off = swz(row, kk * 64 + kblk * 16);
        ah[rt] = *(const sh8*)((char*)Ah + off);
        al[rt] = *(const sh8*)((char*)Al + off);
      }
#pragma unroll
      for (int ct = 0; ct < 4; ++ct) {
        int col = wc * 64 + ct * 16 + lrow;
        int off = swz(col, kk * 64 + kblk * 16);
        bh[ct] = *(const sh8*)((char*)Bh + off);
        bl[ct] = *(const sh8*)((char*)Bl + off);
      }
#pragma unroll
      for (int rt = 0; rt < 2; ++rt)
#pragma unroll
        for (int ct = 0; ct < 4; ++ct) {
          acc[rt][ct] = __builtin_amdgcn_mfma_f32_16x16x32_bf16(ah[rt], bh[ct], acc[rt][ct], 0, 0, 0);
          acc[rt][ct] = __builtin_amdgcn_mfma_f32_16x16x32_bf16(ah[rt], bl[ct], acc[rt][ct], 0, 0, 0);
          acc[rt][ct] = __builtin_amdgcn_mfma_f32_16x16x32_bf16(al[rt], bh[ct], acc[rt][ct], 0, 0, 0);
        }
    }
    __syncthreads();
  }
#pragma unroll
  for (int rt = 0; rt < 2; ++rt)
#pragma unroll
    for (int ct = 0; ct < 4; ++ct)
#pragma unroll
      for (int r = 0; r < 4; ++r) {
        int row = wr * 32 + rt * 16 + kblk * 4 + r;
        int t_ = tok[row];
        if (t_ >= 0) {
          int n = n0 + wc * 64 + ct * 16 + lrow;
          atomicAdd(out + (size_t)t_ * D_MOD + n, gt[row] * acc[rt][ct][r]);
        }
      }
}

// ---------------- launch ----------------

extern "C" void kernel_launch(void* const* d_in, const int* in_sizes, int n_in,
                              void* d_out, int out_size, void* d_ws, size_t ws_size,
                              hipStream_t stream) {
  const float* x  = (const float*)d_in[0];
  const float* Wg = (const float*)d_in[1];
  const float* bg = (const float*)d_in[2];
  const float* W1 = (const float*)d_in[3];
  const float* b1 = (const float*)d_in[4];
  const float* W2 = (const float*)d_in[5];
  const float* b2 = (const float*)d_in[6];
  float* out = (float*)d_out;

  char* ws = (char*)d_ws;
  size_t off = 0;
  auto take = [&](size_t bytes) -> char* {
    char* p = ws + off;
    off += (bytes + 255) & ~(size_t)255;
    return p;
  };
  const size_t WELEMS = (size_t)N_EXP * D_MOD * D_FF;   // 8,388,608
  unsigned short* W1h = (unsigned short*)take(WELEMS * 2);
  unsigned short* W1l = (unsigned short*)take(WELEMS * 2);
  unsigned short* W2h = (unsigned short*)take(WELEMS * 2);
  unsigned short* W2l = (unsigned short*)take(WELEMS * 2);
  int*   top_i      = (int*)take((size_t)T_TOKENS * 2 * 4);
  float* gates      = (float*)take((size_t)T_TOKENS * 2 * 4);
  int*   counts     = (int*)take(64);
  int*   offsets    = (int*)take(64);
  int*   cursor     = (int*)take(64);
  int*   pair_token = (int*)take((size_t)P_CAP * 4);
  float* pair_gate  = (float*)take((size_t)P_CAP * 4);
  float* hbuf       = (float*)(ws + off);
  size_t h_avail = (ws_size > off) ? ws_size - off : 0;
  int rows_cap = (int)(h_avail / ((size_t)D_FF * 4));
  rows_cap &= ~(TM - 1);
  if (rows_cap > P_CAP) rows_cap = P_CAP;
  if (rows_cap < TM) rows_cap = TM;   // if ws is too small this will fail loudly

  k_init<<<dim3((P_CAP + 255) / 256), dim3(256), 0, stream>>>(counts, pair_token, pair_gate);
  k_gate<<<dim3(T_TOKENS / 256), dim3(256), 0, stream>>>(x, Wg, bg, top_i, gates, counts);
  k_scan<<<dim3(1), dim3(64), 0, stream>>>(counts, offsets, cursor);
  k_scatter<<<dim3(T_TOKENS / 256), dim3(256), 0, stream>>>(top_i, gates, cursor, pair_token, pair_gate);
  k_outinit<<<dim3(T_TOKENS * D_MOD / 256), dim3(256), 0, stream>>>(top_i, gates, b2, out);
  // W1[e][512][2048] -> W1t[e][2048][512] ; W2[e][2048][512] -> W2t[e][512][2048]
  k_transpose<<<dim3(D_FF / 32, D_MOD / 32, N_EXP), dim3(256), 0, stream>>>(W1, W1h, W1l, D_MOD, D_FF);
  k_transpose<<<dim3(D_MOD / 32, D_FF / 32, N_EXP), dim3(256), 0, stream>>>(W2, W2h, W2l, D_FF, D_MOD);

  for (int rb = 0; rb < P_CAP; rb += rows_cap) {
    int left = P_CAP - rb;
    int rows = (rows_cap < left) ? rows_cap : left;
    int tiles = rows / TM;
    if (tiles < 1) tiles = 1;
    k_ffn1<<<dim3(tiles, D_FF / 128), dim3(256), 0, stream>>>(x, W1h, W1l, b1, pair_token, offsets, hbuf, rb);
    k_ffn2<<<dim3(tiles, D_MOD / 128), dim3(256), 0, stream>>>(hbuf, W2h, W2l, pair_token, pair_gate, offsets, out, rb);
  }
}